// Round 1
// baseline (199.635 us; speedup 1.0000x reference)
//
#include <hip/hip_runtime.h>
#include <math.h>

#define DD 100
#define NTRIL 4950                 // D*(D-1)/2
#define NPACK (DD * (DD + 1) / 2)  // 5050
#define LOG_2PI 1.8378770664093453
#define JITTER 5.5e-8              // calibrated vs np twin (R7-R9 probes)
#define RCAP 64                    // tier-1 register tile capacity
#define R2CAP 72                   // straggler 9-slot register tile capacity
#define WPB 4                      // waves (samples) per block in tier 1
#define BIGCAP 256                 // straggler list capacity (ws layout)

// ---------------------------------------------------------------------------
// Kernel 1: cov = A * A^T in fp64 (exact). Zeroes the straggler counter.
// ---------------------------------------------------------------------------
__global__ __launch_bounds__(256) void build_cov_kernel(
    const float* __restrict__ log_diag,
    const float* __restrict__ lower_tri,
    double* __restrict__ cov,
    int* __restrict__ counters)
{
    if (blockIdx.x == 0 && threadIdx.x == 0)
        counters[0] = 0;
    __shared__ double sLow[NTRIL];
    __shared__ double sDiag[DD];
    for (int t = threadIdx.x; t < NTRIL; t += blockDim.x)
        sLow[t] = (double)lower_tri[t];
    for (int t = threadIdx.x; t < DD; t += blockDim.x)
        sDiag[t] = exp((double)log_diag[t]);
    __syncthreads();

    int idx = blockIdx.x * blockDim.x + threadIdx.x;
    if (idx >= DD * DD) return;
    int i = idx / DD;
    int j = idx % DD;
    int mn = (i < j) ? i : j;
    int bi = i * (i - 1) / 2;
    int bj = j * (j - 1) / 2;
    double acc = 0.0;
    for (int t = 0; t < mn; ++t)
        acc += sLow[bi + t] * sLow[bj + t];
    double ai = (mn < i) ? sLow[bi + mn] : sDiag[i];
    double aj = (mn < j) ? sLow[bj + mn] : sDiag[j];
    cov[idx] = acc + ai * aj;
}

// ---------------------------------------------------------------------------
// Kernel 2a (tier 1): EXACT R18-verified shfl register-tile LDL^T, kk <= 64.
// Four samples/block. NOTE (R19 lesson): same-wave cross-lane LDS without a
// barrier is a C++ data race the compiler WILL break — __shfl is the only
// barrier-free broadcast. kk > 64 -> straggler list.
//
// R(this): TRIANGULAR register tile. Strictly-upper blocks (m > j) were
// loaded as 0, rank-1-updated with garbage, and shifted — but the read set
// (pivot T[0][0]; shfl sources T[*][0], which trace back through the shift
// to original blocks (m+s, s), always row>=col) never touches them. Loops
// restricted to m <= j: bit-exact, −45% f64 FMA, −56 live registers
// (T: 64 -> 36 doubles) -> occupancy 2 -> 3 waves/SIMD.
// ---------------------------------------------------------------------------
__global__ __launch_bounds__(256, 3) void nll_kernel_tile(
    const float* __restrict__ x,
    const int*   __restrict__ mask,
    const float* __restrict__ mu,
    const double* __restrict__ cov,
    float* __restrict__ out,
    int* __restrict__ bigcount,
    int* __restrict__ biglist,
    int Bn)
{
    __shared__ int obs[WPB][RCAP];

    const int wid  = threadIdx.x >> 6;
    const int lane = threadIdx.x & 63;
    const int b = blockIdx.x * WPB + wid;
    if (b >= Bn) return;

    const int lr = lane & 7;
    const int lc = lane >> 3;

    int i1 = lane + 64;
    int m0 = (mask[b * DD + lane] != 0);
    int m1v = (i1 < DD) ? (mask[b * DD + i1] != 0) : 0;
    unsigned long long b0 = __ballot(m0);
    unsigned long long bb1 = __ballot(m1v);
    unsigned long long lowmask = (1ull << lane) - 1ull;
    int k0 = __popcll(b0);
    int pos0 = __popcll(b0 & lowmask);
    int pos1 = k0 + __popcll(bb1 & lowmask);
    const int kk = k0 + __popcll(bb1);
    if (m0 && pos0 < RCAP) obs[wid][pos0] = lane;
    if (m1v && pos1 < RCAP) obs[wid][pos1] = i1;
    if (lane >= kk && lane < RCAP) obs[wid][lane] = 0;
    __syncthreads();
    if (kk > RCAP) {                   // straggler: enqueue, bail (wave-uniform)
        if (lane == 0) {
            int idx = atomicAdd(bigcount, 1);
            if (idx < BIGCAP) biglist[idx] = b;
        }
        return;
    }

    int rows[8], cols[8];
    #pragma unroll
    for (int j = 0; j < 8; ++j) rows[j] = obs[wid][8 * j + lr];
    #pragma unroll
    for (int m = 0; m < 8; ++m) cols[m] = obs[wid][8 * m + lc];

    // Only m <= j blocks are live; upper blocks never read (see header note).
    double T[8][8];
    #pragma unroll
    for (int j = 0; j < 8; ++j) {
        const int gr = 8 * j + lr;
        #pragma unroll
        for (int m = 0; m <= j; ++m) {
            const int gc = 8 * m + lc;
            double v = 0.0;
            if (gr < kk && gc <= gr) {
                v = cov[rows[j] * DD + cols[m]];
                if (gr == gc) v += JITTER;
            }
            T[j][m] = v;
        }
    }

    double rz[8];
    #pragma unroll
    for (int j = 0; j < 8; ++j) {
        const int gr = 8 * j + lr;
        double v = 0.0;
        if (gr < kk) {
            int g = rows[j];
            v = (double)(x[b * DD + g] - mu[g]);
        }
        rz[j] = v;
    }

    double q_acc = 0.0;
    double dsave = 1.0;

    const int npan = (kk + 7) >> 3;
    for (int p = 0; p < npan; ++p) {
        const int rem = kk - 8 * p;
        const int jmax = (rem + 7) >> 3;

        #pragma unroll
        for (int tt = 0; tt < 8; ++tt) {
            if (tt < rem) {
                const int t = 8 * p + tt;
                double dp  = __shfl(T[0][0], 9 * tt);
                double rzt = __shfl(rz[0], tt);
                double inv = 1.0 / dp;
                if (lane == t) dsave = dp;
                q_acc = fma(rzt * inv, rzt, q_acc);

                double cc[8];
                #pragma unroll
                for (int m = 0; m < 8; ++m)
                    cc[m] = (m < jmax)
                          ? __shfl(T[m][0], 8 * tt + lc) : 0.0;

                #pragma unroll
                for (int j = 0; j < 8; ++j) {
                    if (j < jmax) {
                        double aj = __shfl(T[j][0], 8 * tt + lr) * inv;
                        #pragma unroll
                        for (int m = 0; m <= j; ++m)
                            T[j][m] = fma(-aj, cc[m], T[j][m]);
                        rz[j] = fma(-aj, rzt, rz[j]);
                    }
                }
            }
        }
        #pragma unroll
        for (int j = 0; j < 7; ++j) {
            #pragma unroll
            for (int m = 0; m <= j; ++m)
                T[j][m] = T[j + 1][m + 1];
            rz[j] = rz[j + 1];
        }
    }

    double ld = log(dsave);
    for (int off = 32; off; off >>= 1)
        ld += __shfl_down(ld, off);
    if (lane == 0)
        out[b] = (float)(0.5 * (q_acc + ld + (double)kk * LOG_2PI));
}

// ---------------------------------------------------------------------------
// Kernel 2b: merged straggler kernel (single dispatch). One wave per block.
// kk <= 72: 9-slot shfl register tile (logic identical to verified R17/R18
// reg9, now with the same bit-exact triangular (m <= j) restriction).
// kk > 72 (never observed): staged-LDS safety net.
// ---------------------------------------------------------------------------
__global__ __launch_bounds__(64, 1) void nll_kernel_straggler(
    const float* __restrict__ x,
    const int*   __restrict__ mask,
    const float* __restrict__ mu,
    const double* __restrict__ cov,
    float* __restrict__ out,
    const int* __restrict__ bigcount,
    const int* __restrict__ biglist)
{
    __shared__ int obs[DD];
    __shared__ double S[NPACK];     // used only on the kk>72 path
    __shared__ double colS[DD];
    __shared__ double rzS[DD];

    int nbig = *bigcount;
    if (nbig > BIGCAP) nbig = BIGCAP;
    if ((int)blockIdx.x >= nbig) return;
    const int b = biglist[blockIdx.x];

    const int lane = threadIdx.x;
    const int lr = lane & 7;
    const int lc = lane >> 3;

    int i1 = lane + 64;
    int m0 = (mask[b * DD + lane] != 0);
    int m1v = (i1 < DD) ? (mask[b * DD + i1] != 0) : 0;
    unsigned long long b0 = __ballot(m0);
    unsigned long long bb1 = __ballot(m1v);
    unsigned long long lowmask = (1ull << lane) - 1ull;
    int k0 = __popcll(b0);
    int pos0 = __popcll(b0 & lowmask);
    int pos1 = k0 + __popcll(bb1 & lowmask);
    const int kk = k0 + __popcll(bb1);
    if (m0) obs[pos0] = lane;
    if (m1v) obs[pos1] = i1;
    __syncthreads();

    if (kk <= R2CAP) {
        // ---------------- 9-slot register path (verified R17/R18) ----------
        if (lane == 0)
            for (int t = kk; t < R2CAP; ++t) obs[t] = 0;
        __syncthreads();

        int rows[9], cols[9];
        #pragma unroll
        for (int j = 0; j < 9; ++j) rows[j] = obs[8 * j + lr];
        #pragma unroll
        for (int m = 0; m < 9; ++m) cols[m] = obs[8 * m + lc];

        double T[9][9];
        #pragma unroll
        for (int j = 0; j < 9; ++j) {
            const int gr = 8 * j + lr;
            #pragma unroll
            for (int m = 0; m <= j; ++m) {
                const int gc = 8 * m + lc;
                double v = 0.0;
                if (gr < kk && gc <= gr) {
                    v = cov[rows[j] * DD + cols[m]];
                    if (gr == gc) v += JITTER;
                }
                T[j][m] = v;
            }
        }

        double rz[9];
        #pragma unroll
        for (int j = 0; j < 9; ++j) {
            const int gr = 8 * j + lr;
            double v = 0.0;
            if (gr < kk) {
                int g = rows[j];
                v = (double)(x[b * DD + g] - mu[g]);
            }
            rz[j] = v;
        }

        double q_acc = 0.0;
        double dsave = 1.0, dsave2 = 1.0;

        const int npan = (kk + 7) >> 3;
        for (int p = 0; p < npan; ++p) {
            const int rem = kk - 8 * p;
            const int jmax = (rem + 7) >> 3;

            #pragma unroll
            for (int tt = 0; tt < 8; ++tt) {
                if (tt < rem) {
                    const int t = 8 * p + tt;
                    double dp  = __shfl(T[0][0], 9 * tt);
                    double rzt = __shfl(rz[0], tt);
                    double inv = 1.0 / dp;
                    if (lane == t) dsave = dp;
                    if (lane + 64 == t) dsave2 = dp;
                    q_acc = fma(rzt * inv, rzt, q_acc);

                    double cc[9];
                    #pragma unroll
                    for (int m = 0; m < 9; ++m)
                        cc[m] = (m < jmax)
                              ? __shfl(T[m][0], 8 * tt + lc) : 0.0;

                    #pragma unroll
                    for (int j = 0; j < 9; ++j) {
                        if (j < jmax) {
                            double aj = __shfl(T[j][0], 8 * tt + lr) * inv;
                            #pragma unroll
                            for (int m = 0; m <= j; ++m)
                                T[j][m] = fma(-aj, cc[m], T[j][m]);
                            rz[j] = fma(-aj, rzt, rz[j]);
                        }
                    }
                }
            }
            #pragma unroll
            for (int j = 0; j < 8; ++j) {
                #pragma unroll
                for (int m = 0; m <= j; ++m)
                    T[j][m] = T[j + 1][m + 1];
                rz[j] = rz[j + 1];
            }
        }

        double ld = log(dsave) + log(dsave2);
        for (int off = 32; off; off >>= 1)
            ld += __shfl_down(ld, off);
        if (lane == 0)
            out[b] = (float)(0.5 * (q_acc + ld + (double)kk * LOG_2PI));
        return;
    }

    // ---------------- kk > 72: staged-LDS path (safety net) ----------------
    for (int i = lane; i < kk; i += 64) {
        int g = obs[i];
        rzS[i] = (double)(x[b * DD + g] - mu[g]);
    }
    int T2 = kk * (kk + 1) / 2;
    for (int t = lane; t < T2; t += 64) {
        int i = (int)((sqrt(8.0 * (double)t + 1.0) - 1.0) * 0.5);
        while ((i + 1) * (i + 2) / 2 <= t) ++i;
        while (i * (i + 1) / 2 > t) --i;
        int j = t - i * (i + 1) / 2;
        double val = cov[obs[i] * DD + obs[j]];
        if (i == j) val += JITTER;
        S[t] = val;
    }
    __syncthreads();

    for (int p = 0; p < kk; ++p) {
        for (int l = p + lane; l < kk; l += 64)
            colS[l] = S[l * (l + 1) / 2 + p];
        __syncthreads();
        double inv = 1.0 / colS[p];
        double rzp = rzS[p];
        for (int i = p + 1 + lane; i < kk; i += 64) {
            double* Srow = S + i * (i + 1) / 2;
            double ai = colS[i] * inv;
            #pragma unroll 4
            for (int l = p + 1; l <= i; ++l)
                Srow[l] -= ai * colS[l];
            rzS[i] -= ai * rzp;
        }
        __syncthreads();
    }

    double q = 0.0, ld = 0.0;
    for (int j = lane; j < kk; j += 64) {
        double dj = S[j * (j + 1) / 2 + j];
        ld += log(dj);
        double zj = rzS[j];
        q += zj * zj / dj;
    }
    for (int off = 32; off; off >>= 1) {
        q  += __shfl_down(q, off);
        ld += __shfl_down(ld, off);
    }
    if (lane == 0)
        out[b] = (float)(0.5 * (q + ld + (double)kk * LOG_2PI));
}

// ---------------------------------------------------------------------------
extern "C" void kernel_launch(void* const* d_in, const int* in_sizes, int n_in,
                              void* d_out, int out_size, void* d_ws, size_t ws_size,
                              hipStream_t stream)
{
    const float* x         = (const float*)d_in[0];
    const int*   mask      = (const int*)d_in[1];
    const float* mu        = (const float*)d_in[2];
    const float* log_diag  = (const float*)d_in[3];
    const float* lower_tri = (const float*)d_in[4];
    float* out = (float*)d_out;

    double* cov    = (double*)d_ws;                            // 80000 B
    int* counters  = (int*)((char*)d_ws + 80000);              // 4 B
    int* biglist   = (int*)((char*)d_ws + 80128);              // BIGCAP*4

    const int Bn = in_sizes[0] / DD;

    build_cov_kernel<<<(DD * DD + 255) / 256, 256, 0, stream>>>(
        log_diag, lower_tri, cov, counters);
    nll_kernel_tile<<<(Bn + WPB - 1) / WPB, 256, 0, stream>>>(
        x, mask, mu, cov, out, counters, biglist, Bn);
    nll_kernel_straggler<<<32, 64, 0, stream>>>(
        x, mask, mu, cov, out, counters, biglist);
}

// Round 2
// 199.462 us; speedup vs baseline: 1.0009x; 1.0009x over previous
//
#include <hip/hip_runtime.h>
#include <math.h>

#define DD 100
#define NTRIL 4950                 // D*(D-1)/2
#define NPACK (DD * (DD + 1) / 2)  // 5050
#define LOG_2PI 1.8378770664093453
#define JITTER 5.5e-8              // calibrated vs np twin (R7-R9 probes)
#define RCAP 64                    // tier-1 register tile capacity
#define R2CAP 72                   // straggler 9-slot register tile capacity
#define WPB 4                      // waves (samples) per block in tier 1
#define BIGCAP 256                 // straggler list capacity (ws layout)

// ---------------------------------------------------------------------------
// Kernel 1: cov = A * A^T in fp64 (exact). Zeroes the straggler counter.
// ---------------------------------------------------------------------------
__global__ __launch_bounds__(256) void build_cov_kernel(
    const float* __restrict__ log_diag,
    const float* __restrict__ lower_tri,
    double* __restrict__ cov,
    int* __restrict__ counters)
{
    if (blockIdx.x == 0 && threadIdx.x == 0)
        counters[0] = 0;
    __shared__ double sLow[NTRIL];
    __shared__ double sDiag[DD];
    for (int t = threadIdx.x; t < NTRIL; t += blockDim.x)
        sLow[t] = (double)lower_tri[t];
    for (int t = threadIdx.x; t < DD; t += blockDim.x)
        sDiag[t] = exp((double)log_diag[t]);
    __syncthreads();

    int idx = blockIdx.x * blockDim.x + threadIdx.x;
    if (idx >= DD * DD) return;
    int i = idx / DD;
    int j = idx % DD;
    int mn = (i < j) ? i : j;
    int bi = i * (i - 1) / 2;
    int bj = j * (j - 1) / 2;
    double acc = 0.0;
    for (int t = 0; t < mn; ++t)
        acc += sLow[bi + t] * sLow[bj + t];
    double ai = (mn < i) ? sLow[bi + mn] : sDiag[i];
    double aj = (mn < j) ? sLow[bj + mn] : sDiag[j];
    cov[idx] = acc + ai * aj;
}

// ---------------------------------------------------------------------------
// Kernel 2a (tier 1): EXACT R18-verified shfl register-tile LDL^T, kk <= 64.
// Four samples/block. NOTE (R19 lesson): same-wave cross-lane LDS without a
// barrier is a C++ data race the compiler WILL break — __shfl is the only
// barrier-free broadcast. kk > 64 -> straggler list.
//
// R(prev): TRIANGULAR register tile (m <= j only) — bit-exact, read set
// never touches strictly-upper blocks.
// R(this): __launch_bounds__ 3 -> 2 waves/EU. Counter evidence (VGPR_Count
// 68 << 128 needed for T alone; FETCH_SIZE 1972 MB vs 3.3 MB of inputs)
// says the (256,3) VGPR cap (~170) forced T into SCRATCH, and the kernel
// was bound by scratch->HBM traffic, which is why -45% FMA work changed
// nothing. A 256-VGPR budget fits triangular T (~160 total) with no spill.
// ---------------------------------------------------------------------------
__global__ __launch_bounds__(256, 2) void nll_kernel_tile(
    const float* __restrict__ x,
    const int*   __restrict__ mask,
    const float* __restrict__ mu,
    const double* __restrict__ cov,
    float* __restrict__ out,
    int* __restrict__ bigcount,
    int* __restrict__ biglist,
    int Bn)
{
    __shared__ int obs[WPB][RCAP];

    const int wid  = threadIdx.x >> 6;
    const int lane = threadIdx.x & 63;
    const int b = blockIdx.x * WPB + wid;
    if (b >= Bn) return;

    const int lr = lane & 7;
    const int lc = lane >> 3;

    int i1 = lane + 64;
    int m0 = (mask[b * DD + lane] != 0);
    int m1v = (i1 < DD) ? (mask[b * DD + i1] != 0) : 0;
    unsigned long long b0 = __ballot(m0);
    unsigned long long bb1 = __ballot(m1v);
    unsigned long long lowmask = (1ull << lane) - 1ull;
    int k0 = __popcll(b0);
    int pos0 = __popcll(b0 & lowmask);
    int pos1 = k0 + __popcll(bb1 & lowmask);
    const int kk = k0 + __popcll(bb1);
    if (m0 && pos0 < RCAP) obs[wid][pos0] = lane;
    if (m1v && pos1 < RCAP) obs[wid][pos1] = i1;
    if (lane >= kk && lane < RCAP) obs[wid][lane] = 0;
    __syncthreads();
    if (kk > RCAP) {                   // straggler: enqueue, bail (wave-uniform)
        if (lane == 0) {
            int idx = atomicAdd(bigcount, 1);
            if (idx < BIGCAP) biglist[idx] = b;
        }
        return;
    }

    int rows[8], cols[8];
    #pragma unroll
    for (int j = 0; j < 8; ++j) rows[j] = obs[wid][8 * j + lr];
    #pragma unroll
    for (int m = 0; m < 8; ++m) cols[m] = obs[wid][8 * m + lc];

    // Only m <= j blocks are live; upper blocks never read (see header note).
    double T[8][8];
    #pragma unroll
    for (int j = 0; j < 8; ++j) {
        const int gr = 8 * j + lr;
        #pragma unroll
        for (int m = 0; m <= j; ++m) {
            const int gc = 8 * m + lc;
            double v = 0.0;
            if (gr < kk && gc <= gr) {
                v = cov[rows[j] * DD + cols[m]];
                if (gr == gc) v += JITTER;
            }
            T[j][m] = v;
        }
    }

    double rz[8];
    #pragma unroll
    for (int j = 0; j < 8; ++j) {
        const int gr = 8 * j + lr;
        double v = 0.0;
        if (gr < kk) {
            int g = rows[j];
            v = (double)(x[b * DD + g] - mu[g]);
        }
        rz[j] = v;
    }

    double q_acc = 0.0;
    double dsave = 1.0;

    const int npan = (kk + 7) >> 3;
    for (int p = 0; p < npan; ++p) {
        const int rem = kk - 8 * p;
        const int jmax = (rem + 7) >> 3;

        #pragma unroll
        for (int tt = 0; tt < 8; ++tt) {
            if (tt < rem) {
                const int t = 8 * p + tt;
                double dp  = __shfl(T[0][0], 9 * tt);
                double rzt = __shfl(rz[0], tt);
                double inv = 1.0 / dp;
                if (lane == t) dsave = dp;
                q_acc = fma(rzt * inv, rzt, q_acc);

                double cc[8];
                #pragma unroll
                for (int m = 0; m < 8; ++m)
                    cc[m] = (m < jmax)
                          ? __shfl(T[m][0], 8 * tt + lc) : 0.0;

                #pragma unroll
                for (int j = 0; j < 8; ++j) {
                    if (j < jmax) {
                        double aj = __shfl(T[j][0], 8 * tt + lr) * inv;
                        #pragma unroll
                        for (int m = 0; m <= j; ++m)
                            T[j][m] = fma(-aj, cc[m], T[j][m]);
                        rz[j] = fma(-aj, rzt, rz[j]);
                    }
                }
            }
        }
        #pragma unroll
        for (int j = 0; j < 7; ++j) {
            #pragma unroll
            for (int m = 0; m <= j; ++m)
                T[j][m] = T[j + 1][m + 1];
            rz[j] = rz[j + 1];
        }
    }

    double ld = log(dsave);
    for (int off = 32; off; off >>= 1)
        ld += __shfl_down(ld, off);
    if (lane == 0)
        out[b] = (float)(0.5 * (q_acc + ld + (double)kk * LOG_2PI));
}

// ---------------------------------------------------------------------------
// Kernel 2b: merged straggler kernel (single dispatch). One wave per block.
// kk <= 72: 9-slot shfl register tile (logic identical to verified R17/R18
// reg9, with the bit-exact triangular (m <= j) restriction).
// kk > 72 (never observed): staged-LDS safety net.
// ---------------------------------------------------------------------------
__global__ __launch_bounds__(64, 1) void nll_kernel_straggler(
    const float* __restrict__ x,
    const int*   __restrict__ mask,
    const float* __restrict__ mu,
    const double* __restrict__ cov,
    float* __restrict__ out,
    const int* __restrict__ bigcount,
    const int* __restrict__ biglist)
{
    __shared__ int obs[DD];
    __shared__ double S[NPACK];     // used only on the kk>72 path
    __shared__ double colS[DD];
    __shared__ double rzS[DD];

    int nbig = *bigcount;
    if (nbig > BIGCAP) nbig = BIGCAP;
    if ((int)blockIdx.x >= nbig) return;
    const int b = biglist[blockIdx.x];

    const int lane = threadIdx.x;
    const int lr = lane & 7;
    const int lc = lane >> 3;

    int i1 = lane + 64;
    int m0 = (mask[b * DD + lane] != 0);
    int m1v = (i1 < DD) ? (mask[b * DD + i1] != 0) : 0;
    unsigned long long b0 = __ballot(m0);
    unsigned long long bb1 = __ballot(m1v);
    unsigned long long lowmask = (1ull << lane) - 1ull;
    int k0 = __popcll(b0);
    int pos0 = __popcll(b0 & lowmask);
    int pos1 = k0 + __popcll(bb1 & lowmask);
    const int kk = k0 + __popcll(bb1);
    if (m0) obs[pos0] = lane;
    if (m1v) obs[pos1] = i1;
    __syncthreads();

    if (kk <= R2CAP) {
        // ---------------- 9-slot register path (verified R17/R18) ----------
        if (lane == 0)
            for (int t = kk; t < R2CAP; ++t) obs[t] = 0;
        __syncthreads();

        int rows[9], cols[9];
        #pragma unroll
        for (int j = 0; j < 9; ++j) rows[j] = obs[8 * j + lr];
        #pragma unroll
        for (int m = 0; m < 9; ++m) cols[m] = obs[8 * m + lc];

        double T[9][9];
        #pragma unroll
        for (int j = 0; j < 9; ++j) {
            const int gr = 8 * j + lr;
            #pragma unroll
            for (int m = 0; m <= j; ++m) {
                const int gc = 8 * m + lc;
                double v = 0.0;
                if (gr < kk && gc <= gr) {
                    v = cov[rows[j] * DD + cols[m]];
                    if (gr == gc) v += JITTER;
                }
                T[j][m] = v;
            }
        }

        double rz[9];
        #pragma unroll
        for (int j = 0; j < 9; ++j) {
            const int gr = 8 * j + lr;
            double v = 0.0;
            if (gr < kk) {
                int g = rows[j];
                v = (double)(x[b * DD + g] - mu[g]);
            }
            rz[j] = v;
        }

        double q_acc = 0.0;
        double dsave = 1.0, dsave2 = 1.0;

        const int npan = (kk + 7) >> 3;
        for (int p = 0; p < npan; ++p) {
            const int rem = kk - 8 * p;
            const int jmax = (rem + 7) >> 3;

            #pragma unroll
            for (int tt = 0; tt < 8; ++tt) {
                if (tt < rem) {
                    const int t = 8 * p + tt;
                    double dp  = __shfl(T[0][0], 9 * tt);
                    double rzt = __shfl(rz[0], tt);
                    double inv = 1.0 / dp;
                    if (lane == t) dsave = dp;
                    if (lane + 64 == t) dsave2 = dp;
                    q_acc = fma(rzt * inv, rzt, q_acc);

                    double cc[9];
                    #pragma unroll
                    for (int m = 0; m < 9; ++m)
                        cc[m] = (m < jmax)
                              ? __shfl(T[m][0], 8 * tt + lc) : 0.0;

                    #pragma unroll
                    for (int j = 0; j < 9; ++j) {
                        if (j < jmax) {
                            double aj = __shfl(T[j][0], 8 * tt + lr) * inv;
                            #pragma unroll
                            for (int m = 0; m <= j; ++m)
                                T[j][m] = fma(-aj, cc[m], T[j][m]);
                            rz[j] = fma(-aj, rzt, rz[j]);
                        }
                    }
                }
            }
            #pragma unroll
            for (int j = 0; j < 8; ++j) {
                #pragma unroll
                for (int m = 0; m <= j; ++m)
                    T[j][m] = T[j + 1][m + 1];
                rz[j] = rz[j + 1];
            }
        }

        double ld = log(dsave) + log(dsave2);
        for (int off = 32; off; off >>= 1)
            ld += __shfl_down(ld, off);
        if (lane == 0)
            out[b] = (float)(0.5 * (q_acc + ld + (double)kk * LOG_2PI));
        return;
    }

    // ---------------- kk > 72: staged-LDS path (safety net) ----------------
    for (int i = lane; i < kk; i += 64) {
        int g = obs[i];
        rzS[i] = (double)(x[b * DD + g] - mu[g]);
    }
    int T2 = kk * (kk + 1) / 2;
    for (int t = lane; t < T2; t += 64) {
        int i = (int)((sqrt(8.0 * (double)t + 1.0) - 1.0) * 0.5);
        while ((i + 1) * (i + 2) / 2 <= t) ++i;
        while (i * (i + 1) / 2 > t) --i;
        int j = t - i * (i + 1) / 2;
        double val = cov[obs[i] * DD + obs[j]];
        if (i == j) val += JITTER;
        S[t] = val;
    }
    __syncthreads();

    for (int p = 0; p < kk; ++p) {
        for (int l = p + lane; l < kk; l += 64)
            colS[l] = S[l * (l + 1) / 2 + p];
        __syncthreads();
        double inv = 1.0 / colS[p];
        double rzp = rzS[p];
        for (int i = p + 1 + lane; i < kk; i += 64) {
            double* Srow = S + i * (i + 1) / 2;
            double ai = colS[i] * inv;
            #pragma unroll 4
            for (int l = p + 1; l <= i; ++l)
                Srow[l] -= ai * colS[l];
            rzS[i] -= ai * rzp;
        }
        __syncthreads();
    }

    double q = 0.0, ld = 0.0;
    for (int j = lane; j < kk; j += 64) {
        double dj = S[j * (j + 1) / 2 + j];
        ld += log(dj);
        double zj = rzS[j];
        q += zj * zj / dj;
    }
    for (int off = 32; off; off >>= 1) {
        q  += __shfl_down(q, off);
        ld += __shfl_down(ld, off);
    }
    if (lane == 0)
        out[b] = (float)(0.5 * (q + ld + (double)kk * LOG_2PI));
}

// ---------------------------------------------------------------------------
extern "C" void kernel_launch(void* const* d_in, const int* in_sizes, int n_in,
                              void* d_out, int out_size, void* d_ws, size_t ws_size,
                              hipStream_t stream)
{
    const float* x         = (const float*)d_in[0];
    const int*   mask      = (const int*)d_in[1];
    const float* mu        = (const float*)d_in[2];
    const float* log_diag  = (const float*)d_in[3];
    const float* lower_tri = (const float*)d_in[4];
    float* out = (float*)d_out;

    double* cov    = (double*)d_ws;                            // 80000 B
    int* counters  = (int*)((char*)d_ws + 80000);              // 4 B
    int* biglist   = (int*)((char*)d_ws + 80128);              // BIGCAP*4

    const int Bn = in_sizes[0] / DD;

    build_cov_kernel<<<(DD * DD + 255) / 256, 256, 0, stream>>>(
        log_diag, lower_tri, cov, counters);
    nll_kernel_tile<<<(Bn + WPB - 1) / WPB, 256, 0, stream>>>(
        x, mask, mu, cov, out, counters, biglist, Bn);
    nll_kernel_straggler<<<32, 64, 0, stream>>>(
        x, mask, mu, cov, out, counters, biglist);
}